// Round 7
// baseline (1077.868 us; speedup 1.0000x reference)
//
#include <hip/hip_runtime.h>
#include <hip/hip_cooperative_groups.h>
#include <hip/hip_bf16.h>
#include <math.h>

namespace cg = cooperative_groups;

#define N_V 100000
#define N_E 600000
#define N_F 200000
// CIN = COUT = 128, H = 32

typedef __attribute__((ext_vector_type(8))) short bf16x8;
typedef __attribute__((ext_vector_type(4))) float f32x4;

#define FUSED_BLOCKS 782                    // ceil(100000/128); 128 rows per block
#define FACE_BLOCKS 782                     // ceil(200000/256)
#define EDGE_BLOCKS 2344                    // ceil(600000/256)
#define PACK_BLOCKS 64
#define FRONT_BLOCKS 1536                   // 6 blocks/CU x 256 CU == launch_bounds(256,6) floor
#define BACK_BLOCKS 1536

__device__ __forceinline__ unsigned short f2bf(float f) {
    unsigned int u = __builtin_bit_cast(unsigned int, f);
    u += 0x7fffu + ((u >> 16) & 1u);   // round-to-nearest-even
    return (unsigned short)(u >> 16);
}

// ============================ split-kernel (fallback) path ============================

__global__ void k_fn(const float* __restrict__ vtx, const int* __restrict__ faces,
                     const float* __restrict__ Wlin,
                     float4* __restrict__ fnbuf4,
                     int* __restrict__ head_f, int* __restrict__ next_f,
                     unsigned short* __restrict__ Wb) {
    int b = blockIdx.x;
    int t = threadIdx.x;
    if (b < FACE_BLOCKS) {
        int f = b * 256 + t;
        if (f >= N_F) return;
        int i0 = faces[f], i1 = faces[N_F + f], i2 = faces[2 * N_F + f];
        #pragma unroll
        for (int j = 0; j < 3; j++) {
            int v = (j == 0) ? i0 : (j == 1 ? i1 : i2);
            int c = 3 * f + j;
            int old = atomicExch(&head_f[v], c);
            next_f[c] = old;
        }
        float ax = vtx[3 * i0], ay = vtx[3 * i0 + 1], az = vtx[3 * i0 + 2];
        float bx = vtx[3 * i1] - ax, by = vtx[3 * i1 + 1] - ay, bz = vtx[3 * i1 + 2] - az;
        float cx = vtx[3 * i2] - ax, cy = vtx[3 * i2 + 1] - ay, cz = vtx[3 * i2 + 2] - az;
        float4 fn;
        fn.x = by * cz - bz * cy;
        fn.y = bz * cx - bx * cz;
        fn.z = bx * cy - by * cx;
        fn.w = 0.f;
        fnbuf4[f] = fn;
    } else {
        int i = (b - FACE_BLOCKS) * 256 + t;   // 0..16383
        int j = i & 7;
        int lane = (i >> 3) & 63;
        int ct = (i >> 9) & 7;
        int kk = i >> 12;
        int k = kk * 32 + (lane >> 4) * 8 + j;
        int n = ct * 16 + (lane & 15);
        Wb[i] = f2bf(Wlin[k * 128 + n]);
    }
}

__global__ void k_vnorm(const float4* __restrict__ fnbuf4,
                        const int* __restrict__ head_f, const int* __restrict__ next_f,
                        float4* __restrict__ nrm4) {
    int v = blockIdx.x * 256 + threadIdx.x;
    if (v >= N_V) return;
    float nx = 0.f, ny = 0.f, nz = 0.f;
    int c = head_f[v];
    while (c >= 0) {
        float4 fn = fnbuf4[(unsigned)c / 3u];
        nx += fn.x; ny += fn.y; nz += fn.z;
        c = next_f[c];
    }
    float inv = 1.f / (sqrtf(nx * nx + ny * ny + nz * nz) + 1e-8f);
    float4 o;
    o.x = nx * inv; o.y = ny * inv; o.z = nz * inv; o.w = 0.f;
    nrm4[v] = o;
}

__global__ void k_edge(const float* __restrict__ vtx, const int* __restrict__ edges,
                       const float4* __restrict__ nrm4,
                       const float* __restrict__ W1, const float* __restrict__ b1,
                       const float* __restrict__ W2, const float* __restrict__ b2,
                       int* __restrict__ head_e, uint2* __restrict__ enode) {
    __shared__ float sW1[96], sb1[32], sW2[192], sb2[6];
    int t = threadIdx.x;
    if (t < 96)  sW1[t] = W1[t];
    if (t < 32)  sb1[t] = b1[t];
    if (t < 192) sW2[t] = W2[t];
    if (t < 6)   sb2[t] = b2[t];
    __syncthreads();
    int e = blockIdx.x * blockDim.x + t;
    if (e >= N_E) return;
    int s = edges[e], d = edges[N_E + e];
    int old = atomicExch(&head_e[d], e);
    float4 nv = nrm4[s];
    float dx = vtx[3 * d] - vtx[3 * s];
    float dy = vtx[3 * d + 1] - vtx[3 * s + 1];
    float dz = vtx[3 * d + 2] - vtx[3 * s + 2];
    float nx = nv.x, ny = nv.y, nz = nv.z;
    float dp = dx * nx + dy * ny + dz * nz;
    float tx = dx - dp * nx, ty = dy - dp * ny, tz = dz - dp * nz;
    float th0 = sb2[0], th1 = sb2[1], th2 = sb2[2], th3 = sb2[3], th4 = sb2[4], th5 = sb2[5];
    #pragma unroll
    for (int j = 0; j < 32; j++) {
        float h = tx * sW1[j] + ty * sW1[32 + j] + tz * sW1[64 + j] + sb1[j];
        h = fmaxf(h, 0.f);
        const float* w2r = &sW2[j * 6];
        th0 += h * w2r[0]; th1 += h * w2r[1]; th2 += h * w2r[2];
        th3 += h * w2r[3]; th4 += h * w2r[4]; th5 += h * w2r[5];
    }
    float ux = th0 * tx + th1 * ty + th2 * tz;
    float uy = th1 * tx + th3 * ty + th4 * tz;
    float uz = th2 * tx + th4 * ty + th5 * tz;
    float q = ux * ux + uy * uy + uz * uz;
    float w = expf(-q);
    unsigned int w16 = f2bf(w);
    uint2 nd;
    nd.x = (unsigned int)(old + 1) | ((w16 & 0xFFFu) << 20);
    nd.y = (unsigned int)s | ((w16 >> 12) << 17);
    enode[e] = nd;
}

__global__ __launch_bounds__(64) void k_rstats(const float* __restrict__ partials,
                                               float* __restrict__ stats) {
    int c = blockIdx.x;
    int lane = threadIdx.x;
    float s = 0.f, q = 0.f;
    for (int b = lane; b < FUSED_BLOCKS; b += 64) {
        s += partials[(size_t)b * 256 + c];
        q += partials[(size_t)b * 256 + 128 + c];
    }
    #pragma unroll
    for (int off = 32; off; off >>= 1) {
        s += __shfl_down(s, off);
        q += __shfl_down(q, off);
    }
    if (lane == 0) {
        float mu = s * (1.f / N_V);
        float var = (q - s * mu) * (1.f / (N_V - 1));
        float sd = sqrtf(fmaxf(var, 0.f));
        stats[c] = mu;
        stats[128 + c] = 1.f / (sd + 1e-5f);
    }
}

__global__ void k_finalize(float* __restrict__ out, const float* __restrict__ stats) {
    int i = blockIdx.x * blockDim.x + threadIdx.x;
    if (i >= N_V * 32) return;
    float4 v = ((float4*)out)[i];
    int c0 = (i * 4) & 127;
    float mu0 = stats[c0], mu1 = stats[c0 + 1], mu2 = stats[c0 + 2], mu3 = stats[c0 + 3];
    float is0 = stats[128 + c0], is1 = stats[128 + c0 + 1], is2 = stats[128 + c0 + 2], is3 = stats[128 + c0 + 3];
    v.x = (v.x - mu0) * is0; v.y = (v.y - mu1) * is1;
    v.z = (v.z - mu2) * is2; v.w = (v.w - mu3) * is3;
    v.x = v.x > 0.f ? v.x : expm1f(v.x);
    v.y = v.y > 0.f ? v.y : expm1f(v.y);
    v.z = v.z > 0.f ? v.z : expm1f(v.z);
    v.w = v.w > 0.f ? v.w : expm1f(v.w);
    ((float4*)out)[i] = v;
}

// ============================ cooperative (primary) path ============================

__global__ __launch_bounds__(256, 6) void k_front(
        const float* __restrict__ vtx, const int* __restrict__ faces,
        const float* __restrict__ Wlin, const int* __restrict__ edges,
        const float* __restrict__ W1, const float* __restrict__ b1,
        const float* __restrict__ W2, const float* __restrict__ b2,
        float4* fnbuf4, int* head_f, int* next_f,
        unsigned short* __restrict__ Wb, float4* nrm4,
        int* head_e, uint2* enode) {
    cg::grid_group grid = cg::this_grid();
    int bid = blockIdx.x;
    int t = threadIdx.x;

    // Phase A0: init head arrays to -1 (replaces hipMemsetAsync dispatch)
    int gi = bid * 256 + t;
    if (gi < N_V) head_e[gi] = -1;
    else if (gi < 2 * N_V) head_f[gi - N_V] = -1;
    grid.sync();

    // Phase A: face normals + corner list push (bid<782); Wlin pack (782..845)
    if (bid < FACE_BLOCKS) {
        int f = bid * 256 + t;
        if (f < N_F) {
            int i0 = faces[f], i1 = faces[N_F + f], i2 = faces[2 * N_F + f];
            #pragma unroll
            for (int j = 0; j < 3; j++) {
                int v = (j == 0) ? i0 : (j == 1 ? i1 : i2);
                int c = 3 * f + j;
                int old = atomicExch(&head_f[v], c);
                next_f[c] = old;
            }
            float ax = vtx[3 * i0], ay = vtx[3 * i0 + 1], az = vtx[3 * i0 + 2];
            float bx = vtx[3 * i1] - ax, by = vtx[3 * i1 + 1] - ay, bz = vtx[3 * i1 + 2] - az;
            float cx = vtx[3 * i2] - ax, cy = vtx[3 * i2 + 1] - ay, cz = vtx[3 * i2 + 2] - az;
            float4 fn;
            fn.x = by * cz - bz * cy;
            fn.y = bz * cx - bx * cz;
            fn.z = bx * cy - by * cx;
            fn.w = 0.f;
            fnbuf4[f] = fn;
        }
    } else if (bid < FACE_BLOCKS + PACK_BLOCKS) {
        int i = (bid - FACE_BLOCKS) * 256 + t;
        int j = i & 7;
        int lane = (i >> 3) & 63;
        int ct = (i >> 9) & 7;
        int kk = i >> 12;
        int k = kk * 32 + (lane >> 4) * 8 + j;
        int n = ct * 16 + (lane & 15);
        Wb[i] = f2bf(Wlin[k * 128 + n]);
    }
    grid.sync();

    // Phase B: vertex normals via corner-list walk
    int v = bid * 256 + t;
    if (v < N_V) {
        float nx = 0.f, ny = 0.f, nz = 0.f;
        int c = head_f[v];
        while (c >= 0) {
            float4 fn = fnbuf4[(unsigned)c / 3u];
            nx += fn.x; ny += fn.y; nz += fn.z;
            c = next_f[c];
        }
        float inv = 1.f / (sqrtf(nx * nx + ny * ny + nz * nz) + 1e-8f);
        float4 o;
        o.x = nx * inv; o.y = ny * inv; o.z = nz * inv; o.w = 0.f;
        nrm4[v] = o;
    }
    grid.sync();

    // Phase C: per-edge MLP -> packed node (grid-strided, scalar MLP)
    __shared__ float sW1[96], sb1[32], sW2[192], sb2[6];
    if (t < 96)  sW1[t] = W1[t];
    if (t < 32)  sb1[t] = b1[t];
    if (t < 192) sW2[t] = W2[t];
    if (t < 6)   sb2[t] = b2[t];
    __syncthreads();
    int stride = gridDim.x * 256;
    for (int e = bid * 256 + t; e < N_E; e += stride) {
        int s = edges[e], d = edges[N_E + e];
        int old = atomicExch(&head_e[d], e);
        float4 nv = nrm4[s];
        float dx = vtx[3 * d] - vtx[3 * s];
        float dy = vtx[3 * d + 1] - vtx[3 * s + 1];
        float dz = vtx[3 * d + 2] - vtx[3 * s + 2];
        float nx = nv.x, ny = nv.y, nz = nv.z;
        float dp = dx * nx + dy * ny + dz * nz;
        float tx = dx - dp * nx, ty = dy - dp * ny, tz = dz - dp * nz;
        float th0 = sb2[0], th1 = sb2[1], th2 = sb2[2], th3 = sb2[3], th4 = sb2[4], th5 = sb2[5];
        #pragma unroll
        for (int j = 0; j < 32; j++) {
            float h = tx * sW1[j] + ty * sW1[32 + j] + tz * sW1[64 + j] + sb1[j];
            h = fmaxf(h, 0.f);
            const float* w2r = &sW2[j * 6];
            th0 += h * w2r[0]; th1 += h * w2r[1]; th2 += h * w2r[2];
            th3 += h * w2r[3]; th4 += h * w2r[4]; th5 += h * w2r[5];
        }
        float ux = th0 * tx + th1 * ty + th2 * tz;
        float uy = th1 * tx + th3 * ty + th4 * tz;
        float uz = th2 * tx + th4 * ty + th5 * tz;
        float q = ux * ux + uy * uy + uz * uz;
        float w = expf(-q);
        unsigned int w16 = f2bf(w);
        uint2 nd;
        nd.x = (unsigned int)(old + 1) | ((w16 & 0xFFFu) << 20);
        nd.y = (unsigned int)s | ((w16 >> 12) << 17);
        enode[e] = nd;
    }
}

// --- K4: FUSED aggregate + GEMM + bias + stats partials (UNTOUCHED anchor) ---
__global__ __launch_bounds__(512) void k_fused(const float* __restrict__ feat,
                                               const int* __restrict__ head_e,
                                               const uint2* __restrict__ enode,
                                               const unsigned short* __restrict__ Wb,
                                               const float* __restrict__ blin,
                                               float* __restrict__ out,
                                               float* __restrict__ partials) {
    __shared__ __align__(16) unsigned short At[128 * 136];
    __shared__ float gs[128];
    int t = threadIdx.x;
    int g = t >> 4;
    int gl = t & 15;
    int vb = blockIdx.x * 128 + g * 4;

    float4 a0l = {0,0,0,0}, a0h = {0,0,0,0};
    float4 a1l = {0,0,0,0}, a1h = {0,0,0,0};
    float4 a2l = {0,0,0,0}, a2h = {0,0,0,0};
    float4 a3l = {0,0,0,0}, a3h = {0,0,0,0};
    float d0 = 0.f, d1 = 0.f, d2 = 0.f, d3 = 0.f;
    int e0 = (vb + 0 < N_V) ? head_e[vb + 0] : -1;
    int e1 = (vb + 1 < N_V) ? head_e[vb + 1] : -1;
    int e2 = (vb + 2 < N_V) ? head_e[vb + 2] : -1;
    int e3 = (vb + 3 < N_V) ? head_e[vb + 3] : -1;

    while ((e0 >= 0) || (e1 >= 0) || (e2 >= 0) || (e3 >= 0)) {
        if (e0 >= 0) {
            uint2 nd = enode[e0];
            unsigned int wb = (nd.x >> 20) | (((nd.y >> 17) & 0xFu) << 12);
            float w = __builtin_bit_cast(float, wb << 16);
            const float4* fp = (const float4*)(feat + (size_t)(nd.y & 0x1FFFFu) * 128 + 8 * gl);
            float4 f0 = fp[0], f1 = fp[1];
            a0l.x += w * f0.x; a0l.y += w * f0.y; a0l.z += w * f0.z; a0l.w += w * f0.w;
            a0h.x += w * f1.x; a0h.y += w * f1.y; a0h.z += w * f1.z; a0h.w += w * f1.w;
            d0 += w;
            e0 = (int)(nd.x & 0xFFFFFu) - 1;
        }
        if (e1 >= 0) {
            uint2 nd = enode[e1];
            unsigned int wb = (nd.x >> 20) | (((nd.y >> 17) & 0xFu) << 12);
            float w = __builtin_bit_cast(float, wb << 16);
            const float4* fp = (const float4*)(feat + (size_t)(nd.y & 0x1FFFFu) * 128 + 8 * gl);
            float4 f0 = fp[0], f1 = fp[1];
            a1l.x += w * f0.x; a1l.y += w * f0.y; a1l.z += w * f0.z; a1l.w += w * f0.w;
            a1h.x += w * f1.x; a1h.y += w * f1.y; a1h.z += w * f1.z; a1h.w += w * f1.w;
            d1 += w;
            e1 = (int)(nd.x & 0xFFFFFu) - 1;
        }
        if (e2 >= 0) {
            uint2 nd = enode[e2];
            unsigned int wb = (nd.x >> 20) | (((nd.y >> 17) & 0xFu) << 12);
            float w = __builtin_bit_cast(float, wb << 16);
            const float4* fp = (const float4*)(feat + (size_t)(nd.y & 0x1FFFFu) * 128 + 8 * gl);
            float4 f0 = fp[0], f1 = fp[1];
            a2l.x += w * f0.x; a2l.y += w * f0.y; a2l.z += w * f0.z; a2l.w += w * f0.w;
            a2h.x += w * f1.x; a2h.y += w * f1.y; a2h.z += w * f1.z; a2h.w += w * f1.w;
            d2 += w;
            e2 = (int)(nd.x & 0xFFFFFu) - 1;
        }
        if (e3 >= 0) {
            uint2 nd = enode[e3];
            unsigned int wb = (nd.x >> 20) | (((nd.y >> 17) & 0xFu) << 12);
            float w = __builtin_bit_cast(float, wb << 16);
            const float4* fp = (const float4*)(feat + (size_t)(nd.y & 0x1FFFFu) * 128 + 8 * gl);
            float4 f0 = fp[0], f1 = fp[1];
            a3l.x += w * f0.x; a3l.y += w * f0.y; a3l.z += w * f0.z; a3l.w += w * f0.w;
            a3h.x += w * f1.x; a3h.y += w * f1.y; a3h.z += w * f1.z; a3h.w += w * f1.w;
            d3 += w;
            e3 = (int)(nd.x & 0xFFFFFu) - 1;
        }
    }
    #pragma unroll
    for (int j = 0; j < 4; j++) {
        float4 al = (j == 0) ? a0l : (j == 1) ? a1l : (j == 2) ? a2l : a3l;
        float4 ah = (j == 0) ? a0h : (j == 1) ? a1h : (j == 2) ? a2h : a3h;
        float dn = (j == 0) ? d0 : (j == 1) ? d1 : (j == 2) ? d2 : d3;
        float inv = 1.f / (dn + 1e-5f);
        ushort4 p0, p1;
        p0.x = f2bf(al.x * inv); p0.y = f2bf(al.y * inv);
        p0.z = f2bf(al.z * inv); p0.w = f2bf(al.w * inv);
        p1.x = f2bf(ah.x * inv); p1.y = f2bf(ah.y * inv);
        p1.z = f2bf(ah.z * inv); p1.w = f2bf(ah.w * inv);
        int row = g * 4 + j;
        *(ushort4*)(&At[row * 136 + 8 * gl]) = p0;
        *(ushort4*)(&At[row * 136 + 8 * gl + 4]) = p1;
        if (gl == 0) gs[row] = dn * inv;
    }
    __syncthreads();

    int ct = t >> 6;
    int lane = t & 63;
    int m = lane & 15, quad = lane >> 4;
    bf16x8 bfr[4];
    #pragma unroll
    for (int kk = 0; kk < 4; kk++)
        bfr[kk] = *(const bf16x8*)(Wb + (((kk * 8 + ct) * 64 + lane) << 3));
    float bl = blin[ct * 16 + m];
    float ssr = 0.f, qqr = 0.f;
    #pragma unroll
    for (int tile = 0; tile < 8; tile++) {
        f32x4 acc = (f32x4){0.f, 0.f, 0.f, 0.f};
        #pragma unroll
        for (int kk = 0; kk < 4; kk++) {
            bf16x8 af = *(const bf16x8*)(&At[(tile * 16 + m) * 136 + kk * 32 + quad * 8]);
            acc = __builtin_amdgcn_mfma_f32_16x16x32_bf16(af, bfr[kk], acc, 0, 0, 0);
        }
        int r0 = blockIdx.x * 128 + tile * 16;
        #pragma unroll
        for (int reg = 0; reg < 4; reg++) {
            int r = r0 + quad * 4 + reg;
            float g2 = gs[tile * 16 + quad * 4 + reg];
            float val = acc[reg] + bl * g2;
            if (r < N_V) out[(size_t)r * 128 + ct * 16 + m] = val;
            ssr += val; qqr += val * val;
        }
    }
    ssr += __shfl_xor(ssr, 16); qqr += __shfl_xor(qqr, 16);
    ssr += __shfl_xor(ssr, 32); qqr += __shfl_xor(qqr, 32);
    if (quad == 0) {
        partials[(size_t)blockIdx.x * 256 + ct * 16 + m] = ssr;
        partials[(size_t)blockIdx.x * 256 + 128 + ct * 16 + m] = qqr;
    }
}

__global__ __launch_bounds__(256, 6) void k_back(const float* __restrict__ partials,
                                                 float* __restrict__ stats,
                                                 float* __restrict__ out) {
    cg::grid_group grid = cg::this_grid();
    int bid = blockIdx.x;
    int t = threadIdx.x;

    // Phase A: stats — 128 columns, one wave each (blocks 0..31)
    int gw = bid * 4 + (t >> 6);
    if (gw < 128) {
        int c = gw;
        int lane = t & 63;
        float s = 0.f, q = 0.f;
        for (int b = lane; b < FUSED_BLOCKS; b += 64) {
            s += partials[(size_t)b * 256 + c];
            q += partials[(size_t)b * 256 + 128 + c];
        }
        #pragma unroll
        for (int off = 32; off; off >>= 1) {
            s += __shfl_down(s, off);
            q += __shfl_down(q, off);
        }
        if (lane == 0) {
            float mu = s * (1.f / N_V);
            float var = (q - s * mu) * (1.f / (N_V - 1));
            float sd = sqrtf(fmaxf(var, 0.f));
            stats[c] = mu;
            stats[128 + c] = 1.f / (sd + 1e-5f);
        }
    }
    grid.sync();

    // Phase B: normalize + ELU, grid-strided float4
    int stride = gridDim.x * 256;
    for (int i = bid * 256 + t; i < N_V * 32; i += stride) {
        float4 v = ((float4*)out)[i];
        int c0 = (i * 4) & 127;
        float mu0 = stats[c0], mu1 = stats[c0 + 1], mu2 = stats[c0 + 2], mu3 = stats[c0 + 3];
        float is0 = stats[128 + c0], is1 = stats[128 + c0 + 1], is2 = stats[128 + c0 + 2], is3 = stats[128 + c0 + 3];
        v.x = (v.x - mu0) * is0; v.y = (v.y - mu1) * is1;
        v.z = (v.z - mu2) * is2; v.w = (v.w - mu3) * is3;
        v.x = v.x > 0.f ? v.x : expm1f(v.x);
        v.y = v.y > 0.f ? v.y : expm1f(v.y);
        v.z = v.z > 0.f ? v.z : expm1f(v.z);
        v.w = v.w > 0.f ? v.w : expm1f(v.w);
        ((float4*)out)[i] = v;
    }
}

extern "C" void kernel_launch(void* const* d_in, const int* in_sizes, int n_in,
                              void* d_out, int out_size, void* d_ws, size_t ws_size,
                              hipStream_t stream) {
    const float* feat  = (const float*)d_in[0];
    const float* vtx   = (const float*)d_in[1];
    const int*   edges = (const int*)d_in[2];
    const int*   faces = (const int*)d_in[3];
    const float* W1   = (const float*)d_in[4];
    const float* b1   = (const float*)d_in[5];
    const float* W2   = (const float*)d_in[6];
    const float* b2   = (const float*)d_in[7];
    const float* Wlin = (const float*)d_in[8];
    const float* blin = (const float*)d_in[9];
    float* out = (float*)d_out;

    float* ws = (float*)d_ws;
    // Workspace layout (peak 2,008,320 floats = 8.03 MB < proven-safe 8.83 MB):
    //   head_e   [0..100000)        ; stats aliases [0..256) after k_fused
    //   head_f   [100000..200000)
    //   nrm4     [200000..600000)   ; partials [100000..300192) aliases after k_edge
    //   next_f   [600128..1200128)  ; fnbuf4 [1200128..2000128)
    //   enode    [600128..1800128)  aliases next_f+fnbuf4 after vnorm
    //   Wb       [2000128..2008320)
    int*   head_e   = (int*)ws;
    int*   head_f   = (int*)(ws + 100000);
    float4* nrm4    = (float4*)(ws + 200000);
    float* partials = ws + 100000;
    int*   next_f   = (int*)(ws + 600128);
    float4* fnbuf4  = (float4*)(ws + 1200128);
    uint2* enode    = (uint2*)(ws + 600128);
    unsigned short* Wb = (unsigned short*)(ws + 2000128);
    float* stats    = ws;

    // --- front: cooperative, with host-side fallback to the proven split path ---
    void* frontArgs[] = {
        (void*)&vtx, (void*)&faces, (void*)&Wlin, (void*)&edges,
        (void*)&W1, (void*)&b1, (void*)&W2, (void*)&b2,
        (void*)&fnbuf4, (void*)&head_f, (void*)&next_f,
        (void*)&Wb, (void*)&nrm4, (void*)&head_e, (void*)&enode
    };
    hipError_t fe = hipLaunchCooperativeKernel((const void*)k_front, dim3(FRONT_BLOCKS),
                                               dim3(256), frontArgs, 0, stream);
    if (fe != hipSuccess) {
        hipMemsetAsync(head_e, 0xFF, 200000 * sizeof(int), stream);   // head_e + head_f
        k_fn<<<FACE_BLOCKS + PACK_BLOCKS, 256, 0, stream>>>(vtx, faces, Wlin, fnbuf4,
                                                            head_f, next_f, Wb);
        k_vnorm<<<(N_V + 255) / 256, 256, 0, stream>>>(fnbuf4, head_f, next_f, nrm4);
        k_edge<<<EDGE_BLOCKS, 256, 0, stream>>>(vtx, edges, nrm4, W1, b1, W2, b2,
                                                head_e, enode);
    }

    k_fused<<<FUSED_BLOCKS, 512, 0, stream>>>(feat, head_e, enode, Wb, blin,
                                              out, partials);

    // --- back: cooperative, with fallback ---
    void* backArgs[] = { (void*)&partials, (void*)&stats, (void*)&out };
    hipError_t be = hipLaunchCooperativeKernel((const void*)k_back, dim3(BACK_BLOCKS),
                                               dim3(256), backArgs, 0, stream);
    if (be != hipSuccess) {
        k_rstats<<<128, 64, 0, stream>>>(partials, stats);
        k_finalize<<<(N_V * 32 + 255) / 256, 256, 0, stream>>>(out, stats);
    }
}

// Round 8
// 267.220 us; speedup vs baseline: 4.0336x; 4.0336x over previous
//
#include <hip/hip_runtime.h>
#include <hip/hip_bf16.h>
#include <math.h>

#define N_V 100000
#define N_E 600000
#define N_F 200000
// CIN = COUT = 128, H = 32

typedef __attribute__((ext_vector_type(8))) short bf16x8;
typedef __attribute__((ext_vector_type(4))) float f32x4;

#define FUSED_BLOCKS 782                    // ceil(100000/128); 128 rows per block
#define FACE_BLOCKS 782                     // ceil(200000/256)
#define EDGE_BLOCKS 2344                    // ceil(600000/256)
#define PACK_BLOCKS 64

__device__ __forceinline__ unsigned short f2bf(float f) {
    unsigned int u = __builtin_bit_cast(unsigned int, f);
    u += 0x7fffu + ((u >> 16) & 1u);   // round-to-nearest-even
    return (unsigned short)(u >> 16);
}

// --- K1: per-face normals (float4, streamed) + corner linked-list push + Wlin pack ---
// (atomicAdd variant measured 97us @ 18.6G atomics/s — list build is cheaper.
//  cooperative grid.sync variant measured 835us/900MB spin traffic — retired.)
__global__ void k_fn(const float* __restrict__ vtx, const int* __restrict__ faces,
                     const float* __restrict__ Wlin,
                     float4* __restrict__ fnbuf4,
                     int* __restrict__ head_f, int* __restrict__ next_f,
                     unsigned short* __restrict__ Wb) {
    int b = blockIdx.x;
    int t = threadIdx.x;
    if (b < FACE_BLOCKS) {
        int f = b * 256 + t;
        if (f >= N_F) return;
        int i0 = faces[f], i1 = faces[N_F + f], i2 = faces[2 * N_F + f];
        // push corners first so the exch latency overlaps the vtx gathers
        #pragma unroll
        for (int j = 0; j < 3; j++) {
            int v = (j == 0) ? i0 : (j == 1 ? i1 : i2);
            int c = 3 * f + j;
            int old = atomicExch(&head_f[v], c);
            next_f[c] = old;
        }
        float ax = vtx[3 * i0], ay = vtx[3 * i0 + 1], az = vtx[3 * i0 + 2];
        float bx = vtx[3 * i1] - ax, by = vtx[3 * i1 + 1] - ay, bz = vtx[3 * i1 + 2] - az;
        float cx = vtx[3 * i2] - ax, cy = vtx[3 * i2 + 1] - ay, cz = vtx[3 * i2 + 2] - az;
        float4 fn;
        fn.x = by * cz - bz * cy;
        fn.y = bz * cx - bx * cz;
        fn.z = bx * cy - by * cx;
        fn.w = 0.f;
        fnbuf4[f] = fn;
    } else {
        // pack Wlin (fp32 [128,128]) into bf16 MFMA B-fragment order
        int i = (b - FACE_BLOCKS) * 256 + t;   // 0..16383
        int j = i & 7;
        int lane = (i >> 3) & 63;
        int ct = (i >> 9) & 7;
        int kk = i >> 12;
        int k = kk * 32 + (lane >> 4) * 8 + j;
        int n = ct * 16 + (lane & 15);
        Wb[i] = f2bf(Wlin[k * 128 + n]);
    }
}

// --- K2: vertex normals via corner-list walk; output float4 (coalesced, vec-gatherable) ---
__global__ void k_vnorm(const float4* __restrict__ fnbuf4,
                        const int* __restrict__ head_f, const int* __restrict__ next_f,
                        float4* __restrict__ nrm4) {
    int v = blockIdx.x * 256 + threadIdx.x;
    if (v >= N_V) return;
    float nx = 0.f, ny = 0.f, nz = 0.f;
    int c = head_f[v];
    while (c >= 0) {
        float4 fn = fnbuf4[(unsigned)c / 3u];
        nx += fn.x; ny += fn.y; nz += fn.z;
        c = next_f[c];
    }
    float inv = 1.f / (sqrtf(nx * nx + ny * ny + nz * nz) + 1e-8f);
    float4 o;
    o.x = nx * inv; o.y = ny * inv; o.z = nz * inv; o.w = 0.f;
    nrm4[v] = o;
}

// --- K3: per-edge MLP -> packed node {src, next+1, w_bf16} in one uint2 ---
__global__ void k_edge(const float* __restrict__ vtx, const int* __restrict__ edges,
                       const float4* __restrict__ nrm4,
                       const float* __restrict__ W1, const float* __restrict__ b1,
                       const float* __restrict__ W2, const float* __restrict__ b2,
                       int* __restrict__ head_e, uint2* __restrict__ enode) {
    __shared__ float sW1[96], sb1[32], sW2[192], sb2[6];
    int t = threadIdx.x;
    if (t < 96)  sW1[t] = W1[t];
    if (t < 32)  sb1[t] = b1[t];
    if (t < 192) sW2[t] = W2[t];
    if (t < 6)   sb2[t] = b2[t];
    __syncthreads();
    int e = blockIdx.x * blockDim.x + t;
    if (e >= N_E) return;
    int s = edges[e], d = edges[N_E + e];
    int old = atomicExch(&head_e[d], e);      // issue early; latency hides under MLP
    float4 nv = nrm4[s];                      // one 16B gather instead of 3 scalars
    float dx = vtx[3 * d] - vtx[3 * s];
    float dy = vtx[3 * d + 1] - vtx[3 * s + 1];
    float dz = vtx[3 * d + 2] - vtx[3 * s + 2];
    float nx = nv.x, ny = nv.y, nz = nv.z;
    float dp = dx * nx + dy * ny + dz * nz;
    float tx = dx - dp * nx, ty = dy - dp * ny, tz = dz - dp * nz;
    float th0 = sb2[0], th1 = sb2[1], th2 = sb2[2], th3 = sb2[3], th4 = sb2[4], th5 = sb2[5];
    #pragma unroll
    for (int j = 0; j < 32; j++) {
        float h = tx * sW1[j] + ty * sW1[32 + j] + tz * sW1[64 + j] + sb1[j];
        h = fmaxf(h, 0.f);
        const float* w2r = &sW2[j * 6];
        th0 += h * w2r[0]; th1 += h * w2r[1]; th2 += h * w2r[2];
        th3 += h * w2r[3]; th4 += h * w2r[4]; th5 += h * w2r[5];
    }
    // S symmetric; q = ||S t||^2
    float ux = th0 * tx + th1 * ty + th2 * tz;
    float uy = th1 * tx + th3 * ty + th4 * tz;
    float uz = th2 * tx + th4 * ty + th5 * tz;
    float q = ux * ux + uy * uy + uz * uz;
    float w = expf(-q);
    unsigned int w16 = f2bf(w);
    uint2 nd;
    nd.x = (unsigned int)(old + 1) | ((w16 & 0xFFFu) << 20);   // next+1 (20b) | w lo12
    nd.y = (unsigned int)s | ((w16 >> 12) << 17);              // src (17b) | w hi4
    enode[e] = nd;
}

// --- K4: FUSED aggregate + GEMM + bias + stats partials. (proven shape: 512 thr,
// 128 rows, VGPR 32. NEW this round: non-temporal out stores so the 51MB out
// stream doesn't evict feat from L2/L3 — FETCH_SIZE 169MB says feat re-fetched 3x.)
__global__ __launch_bounds__(512) void k_fused(const float* __restrict__ feat,
                                               const int* __restrict__ head_e,
                                               const uint2* __restrict__ enode,
                                               const unsigned short* __restrict__ Wb,
                                               const float* __restrict__ blin,
                                               float* __restrict__ out,
                                               float* __restrict__ partials) {
    __shared__ __align__(16) unsigned short At[128 * 136];
    __shared__ float gs[128];
    int t = threadIdx.x;
    int g = t >> 4;             // 16-lane group 0..31
    int gl = t & 15;            // lane in group
    int vb = blockIdx.x * 128 + g * 4;   // this group owns rows g*4 .. g*4+3

    float4 a0l = {0,0,0,0}, a0h = {0,0,0,0};
    float4 a1l = {0,0,0,0}, a1h = {0,0,0,0};
    float4 a2l = {0,0,0,0}, a2h = {0,0,0,0};
    float4 a3l = {0,0,0,0}, a3h = {0,0,0,0};
    float d0 = 0.f, d1 = 0.f, d2 = 0.f, d3 = 0.f;
    int e0 = (vb + 0 < N_V) ? head_e[vb + 0] : -1;
    int e1 = (vb + 1 < N_V) ? head_e[vb + 1] : -1;
    int e2 = (vb + 2 < N_V) ? head_e[vb + 2] : -1;
    int e3 = (vb + 3 < N_V) ? head_e[vb + 3] : -1;

    while ((e0 >= 0) || (e1 >= 0) || (e2 >= 0) || (e3 >= 0)) {
        if (e0 >= 0) {
            uint2 nd = enode[e0];
            unsigned int wb = (nd.x >> 20) | (((nd.y >> 17) & 0xFu) << 12);
            float w = __builtin_bit_cast(float, wb << 16);
            const float4* fp = (const float4*)(feat + (size_t)(nd.y & 0x1FFFFu) * 128 + 8 * gl);
            float4 f0 = fp[0], f1 = fp[1];
            a0l.x += w * f0.x; a0l.y += w * f0.y; a0l.z += w * f0.z; a0l.w += w * f0.w;
            a0h.x += w * f1.x; a0h.y += w * f1.y; a0h.z += w * f1.z; a0h.w += w * f1.w;
            d0 += w;
            e0 = (int)(nd.x & 0xFFFFFu) - 1;
        }
        if (e1 >= 0) {
            uint2 nd = enode[e1];
            unsigned int wb = (nd.x >> 20) | (((nd.y >> 17) & 0xFu) << 12);
            float w = __builtin_bit_cast(float, wb << 16);
            const float4* fp = (const float4*)(feat + (size_t)(nd.y & 0x1FFFFu) * 128 + 8 * gl);
            float4 f0 = fp[0], f1 = fp[1];
            a1l.x += w * f0.x; a1l.y += w * f0.y; a1l.z += w * f0.z; a1l.w += w * f0.w;
            a1h.x += w * f1.x; a1h.y += w * f1.y; a1h.z += w * f1.z; a1h.w += w * f1.w;
            d1 += w;
            e1 = (int)(nd.x & 0xFFFFFu) - 1;
        }
        if (e2 >= 0) {
            uint2 nd = enode[e2];
            unsigned int wb = (nd.x >> 20) | (((nd.y >> 17) & 0xFu) << 12);
            float w = __builtin_bit_cast(float, wb << 16);
            const float4* fp = (const float4*)(feat + (size_t)(nd.y & 0x1FFFFu) * 128 + 8 * gl);
            float4 f0 = fp[0], f1 = fp[1];
            a2l.x += w * f0.x; a2l.y += w * f0.y; a2l.z += w * f0.z; a2l.w += w * f0.w;
            a2h.x += w * f1.x; a2h.y += w * f1.y; a2h.z += w * f1.z; a2h.w += w * f1.w;
            d2 += w;
            e2 = (int)(nd.x & 0xFFFFFu) - 1;
        }
        if (e3 >= 0) {
            uint2 nd = enode[e3];
            unsigned int wb = (nd.x >> 20) | (((nd.y >> 17) & 0xFu) << 12);
            float w = __builtin_bit_cast(float, wb << 16);
            const float4* fp = (const float4*)(feat + (size_t)(nd.y & 0x1FFFFu) * 128 + 8 * gl);
            float4 f0 = fp[0], f1 = fp[1];
            a3l.x += w * f0.x; a3l.y += w * f0.y; a3l.z += w * f0.z; a3l.w += w * f0.w;
            a3h.x += w * f1.x; a3h.y += w * f1.y; a3h.z += w * f1.z; a3h.w += w * f1.w;
            d3 += w;
            e3 = (int)(nd.x & 0xFFFFFu) - 1;
        }
    }
    #pragma unroll
    for (int j = 0; j < 4; j++) {
        float4 al = (j == 0) ? a0l : (j == 1) ? a1l : (j == 2) ? a2l : a3l;
        float4 ah = (j == 0) ? a0h : (j == 1) ? a1h : (j == 2) ? a2h : a3h;
        float dn = (j == 0) ? d0 : (j == 1) ? d1 : (j == 2) ? d2 : d3;
        float inv = 1.f / (dn + 1e-5f);
        ushort4 p0, p1;
        p0.x = f2bf(al.x * inv); p0.y = f2bf(al.y * inv);
        p0.z = f2bf(al.z * inv); p0.w = f2bf(al.w * inv);
        p1.x = f2bf(ah.x * inv); p1.y = f2bf(ah.y * inv);
        p1.z = f2bf(ah.z * inv); p1.w = f2bf(ah.w * inv);
        int row = g * 4 + j;
        *(ushort4*)(&At[row * 136 + 8 * gl]) = p0;
        *(ushort4*)(&At[row * 136 + 8 * gl + 4]) = p1;
        if (gl == 0) gs[row] = dn * inv;
    }
    __syncthreads();

    // Phase 2: MFMA. wave id = column tile ct; 8 row tiles of 16.
    int ct = t >> 6;
    int lane = t & 63;
    int m = lane & 15, quad = lane >> 4;
    bf16x8 bfr[4];
    #pragma unroll
    for (int kk = 0; kk < 4; kk++)
        bfr[kk] = *(const bf16x8*)(Wb + (((kk * 8 + ct) * 64 + lane) << 3));
    float bl = blin[ct * 16 + m];
    float ssr = 0.f, qqr = 0.f;
    #pragma unroll
    for (int tile = 0; tile < 8; tile++) {
        f32x4 acc = (f32x4){0.f, 0.f, 0.f, 0.f};
        #pragma unroll
        for (int kk = 0; kk < 4; kk++) {
            bf16x8 af = *(const bf16x8*)(&At[(tile * 16 + m) * 136 + kk * 32 + quad * 8]);
            acc = __builtin_amdgcn_mfma_f32_16x16x32_bf16(af, bfr[kk], acc, 0, 0, 0);
        }
        int r0 = blockIdx.x * 128 + tile * 16;
        #pragma unroll
        for (int reg = 0; reg < 4; reg++) {
            int r = r0 + quad * 4 + reg;
            float g2 = gs[tile * 16 + quad * 4 + reg];
            float val = acc[reg] + bl * g2;
            if (r < N_V)
                __builtin_nontemporal_store(val, &out[(size_t)r * 128 + ct * 16 + m]);
            ssr += val; qqr += val * val;   // invalid rows contribute exactly 0
        }
    }
    ssr += __shfl_xor(ssr, 16); qqr += __shfl_xor(qqr, 16);
    ssr += __shfl_xor(ssr, 32); qqr += __shfl_xor(qqr, 32);
    if (quad == 0) {
        partials[(size_t)blockIdx.x * 256 + ct * 16 + m] = ssr;
        partials[(size_t)blockIdx.x * 256 + 128 + ct * 16 + m] = qqr;
    }
}

// --- K5: parallel partials reduction: one wave per column ---
__global__ __launch_bounds__(64) void k_rstats(const float* __restrict__ partials,
                                               float* __restrict__ stats) {
    int c = blockIdx.x;          // 0..127
    int lane = threadIdx.x;      // 0..63
    float s = 0.f, q = 0.f;
    for (int b = lane; b < FUSED_BLOCKS; b += 64) {
        s += partials[(size_t)b * 256 + c];
        q += partials[(size_t)b * 256 + 128 + c];
    }
    #pragma unroll
    for (int off = 32; off; off >>= 1) {
        s += __shfl_down(s, off);
        q += __shfl_down(q, off);
    }
    if (lane == 0) {
        float mu = s * (1.f / N_V);
        float var = (q - s * mu) * (1.f / (N_V - 1));
        float sd = sqrtf(fmaxf(var, 0.f));
        stats[c] = mu;
        stats[128 + c] = 1.f / (sd + 1e-5f);
    }
}

// --- K6: normalize + ELU, in place, float4 ---
__global__ void k_finalize(float* __restrict__ out, const float* __restrict__ stats) {
    int i = blockIdx.x * blockDim.x + threadIdx.x;
    if (i >= N_V * 32) return;
    float4 v = ((float4*)out)[i];
    int c0 = (i * 4) & 127;
    float mu0 = stats[c0], mu1 = stats[c0 + 1], mu2 = stats[c0 + 2], mu3 = stats[c0 + 3];
    float is0 = stats[128 + c0], is1 = stats[128 + c0 + 1], is2 = stats[128 + c0 + 2], is3 = stats[128 + c0 + 3];
    v.x = (v.x - mu0) * is0; v.y = (v.y - mu1) * is1;
    v.z = (v.z - mu2) * is2; v.w = (v.w - mu3) * is3;
    v.x = v.x > 0.f ? v.x : expm1f(v.x);
    v.y = v.y > 0.f ? v.y : expm1f(v.y);
    v.z = v.z > 0.f ? v.z : expm1f(v.z);
    v.w = v.w > 0.f ? v.w : expm1f(v.w);
    ((float4*)out)[i] = v;
}

extern "C" void kernel_launch(void* const* d_in, const int* in_sizes, int n_in,
                              void* d_out, int out_size, void* d_ws, size_t ws_size,
                              hipStream_t stream) {
    const float* feat  = (const float*)d_in[0];
    const float* vtx   = (const float*)d_in[1];
    const int*   edges = (const int*)d_in[2];
    const int*   faces = (const int*)d_in[3];
    const float* W1   = (const float*)d_in[4];
    const float* b1   = (const float*)d_in[5];
    const float* W2   = (const float*)d_in[6];
    const float* b2   = (const float*)d_in[7];
    const float* Wlin = (const float*)d_in[8];
    const float* blin = (const float*)d_in[9];
    float* out = (float*)d_out;

    float* ws = (float*)d_ws;
    // Workspace: peak 2,008,320 floats (8.03 MB) < proven-safe 8.83 MB. Liveness:
    //   head_e   [0..100000)        : memset .. k_fused; stats ALIASES [0..256) after
    //   head_f   [100000..200000)   : memset .. k_vnorm (contiguous with head_e -> 1 memset)
    //   nrm4     [200000..600000)   : k_vnorm .. k_edge (float4 x 100000)
    //   partials [100000..300192)   : ALIAS head_f+nrm4 — k_fused .. k_rstats (both dead)
    //   next_f   [600128..1200128)  : k_fn .. k_vnorm
    //   fnbuf4   [1200128..2000128) : k_fn .. k_vnorm (200000 float4)
    //   enode    [600128..1800128)  : ALIAS next_f+fnbuf4 — k_edge .. k_fused
    //   Wb       [2000128..2008320) : k_fn .. k_fused (16384 shorts)
    int*   head_e   = (int*)ws;                              // 100000
    int*   head_f   = (int*)(ws + 100000);                   // 100000
    float4* nrm4    = (float4*)(ws + 200000);                // 100000 float4
    float* partials = ws + 100000;                           // 200192 (alias)
    int*   next_f   = (int*)(ws + 600128);                   // 600000
    float4* fnbuf4  = (float4*)(ws + 1200128);               // 200000 float4
    uint2* enode    = (uint2*)(ws + 600128);                 // 600000 uint2 (alias)
    unsigned short* Wb = (unsigned short*)(ws + 2000128);    // 16384 shorts
    float* stats    = ws;                                    // 256 (alias, head_e dead)

    hipMemsetAsync(head_e, 0xFF, 200000 * sizeof(int), stream);   // head_e + head_f

    k_fn<<<FACE_BLOCKS + PACK_BLOCKS, 256, 0, stream>>>(vtx, faces, Wlin, fnbuf4,
                                                        head_f, next_f, Wb);
    k_vnorm<<<(N_V + 255) / 256, 256, 0, stream>>>(fnbuf4, head_f, next_f, nrm4);
    k_edge<<<EDGE_BLOCKS, 256, 0, stream>>>(vtx, edges, nrm4, W1, b1, W2, b2,
                                            head_e, enode);
    k_fused<<<FUSED_BLOCKS, 512, 0, stream>>>(feat, head_e, enode, Wb, blin,
                                              out, partials);
    k_rstats<<<128, 64, 0, stream>>>(partials, stats);
    k_finalize<<<(N_V * 32 + 255) / 256, 256, 0, stream>>>(out, stats);
}

// Round 10
// 263.563 us; speedup vs baseline: 4.0896x; 1.0139x over previous
//
#include <hip/hip_runtime.h>
#include <hip/hip_bf16.h>
#include <math.h>

#define N_V 100000
#define N_E 600000
#define N_F 200000
// CIN = COUT = 128, H = 32

typedef __attribute__((ext_vector_type(8))) short bf16x8;
typedef __attribute__((ext_vector_type(4))) float f32x4;

#define FUSED_BLOCKS 782                    // ceil(100000/128); 128 rows per block
#define FACE_BLOCKS 782                     // ceil(200000/256)
#define EDGE_BLOCKS 2344                    // ceil(600000/256)
#define PACK_BLOCKS 64
#define CONV_BLOCKS 6250                    // 100000*128 bf16 conversions / (256*8)

__device__ __forceinline__ unsigned short f2bf(float f) {
    unsigned int u = __builtin_bit_cast(unsigned int, f);
    u += 0x7fffu + ((u >> 16) & 1u);   // round-to-nearest-even
    return (unsigned short)(u >> 16);
}
__device__ __forceinline__ float bf2f(short s) {
    return __builtin_bit_cast(float, ((unsigned int)(unsigned short)s) << 16);
}

// --- K1: faces (normals + corner list push) + Wlin pack, and — when the grid is
// launched larger (tier>=1) — the edge list-push segment and (tier 2) feat->bf16
// conversion segment. All segments independent; atomics overlap streaming work.
// (atomicAdd normals: 97us. cooperative grid.sync: 835us. both retired.)
__global__ void k_fn(const float* __restrict__ vtx, const int* __restrict__ faces,
                     const float* __restrict__ Wlin, const int* __restrict__ edges,
                     const float* __restrict__ feat,
                     float4* __restrict__ fnbuf4,
                     int* __restrict__ head_f, int* __restrict__ next_f,
                     unsigned short* __restrict__ Wb,
                     int* __restrict__ head_e, uint2* __restrict__ enode,
                     unsigned short* __restrict__ featb) {
    int b = blockIdx.x;
    int t = threadIdx.x;
    if (b < FACE_BLOCKS) {
        int f = b * 256 + t;
        if (f >= N_F) return;
        int i0 = faces[f], i1 = faces[N_F + f], i2 = faces[2 * N_F + f];
        #pragma unroll
        for (int j = 0; j < 3; j++) {
            int v = (j == 0) ? i0 : (j == 1 ? i1 : i2);
            int c = 3 * f + j;
            int old = atomicExch(&head_f[v], c);
            next_f[c] = old;
        }
        float ax = vtx[3 * i0], ay = vtx[3 * i0 + 1], az = vtx[3 * i0 + 2];
        float bx = vtx[3 * i1] - ax, by = vtx[3 * i1 + 1] - ay, bz = vtx[3 * i1 + 2] - az;
        float cx = vtx[3 * i2] - ax, cy = vtx[3 * i2 + 1] - ay, cz = vtx[3 * i2 + 2] - az;
        float4 fn;
        fn.x = by * cz - bz * cy;
        fn.y = bz * cx - bx * cz;
        fn.z = bx * cy - by * cx;
        fn.w = 0.f;
        fnbuf4[f] = fn;
    } else if (b < FACE_BLOCKS + PACK_BLOCKS) {
        // pack Wlin (fp32 [128,128]) into bf16 MFMA B-fragment order
        int i = (b - FACE_BLOCKS) * 256 + t;   // 0..16383
        int j = i & 7;
        int lane = (i >> 3) & 63;
        int ct = (i >> 9) & 7;
        int kk = i >> 12;
        int k = kk * 32 + (lane >> 4) * 8 + j;
        int n = ct * 16 + (lane & 15);
        Wb[i] = f2bf(Wlin[k * 128 + n]);
    } else if (b < FACE_BLOCKS + PACK_BLOCKS + EDGE_BLOCKS) {
        // tier>=1: edge list push (atomic-free k_edge then only fills w)
        int e = (b - FACE_BLOCKS - PACK_BLOCKS) * 256 + t;
        if (e >= N_E) return;
        int s = edges[e], d = edges[N_E + e];
        int old = atomicExch(&head_e[d], e);
        uint2 nd;
        nd.x = (unsigned int)(old + 1);        // next+1 (20 bits used)
        nd.y = (unsigned int)s;                // src; k_edge ORs w<<17 later
        enode[e] = nd;
    } else {
        // tier 2: feat fp32 -> bf16 row-major copy (streamed, 8 elems/thread)
        int i = (b - FACE_BLOCKS - PACK_BLOCKS - EDGE_BLOCKS) * 256 + t;
        const float4* fp = (const float4*)(feat + (size_t)i * 8);
        float4 f0 = fp[0], f1 = fp[1];
        bf16x8 p;
        p[0] = (short)f2bf(f0.x); p[1] = (short)f2bf(f0.y);
        p[2] = (short)f2bf(f0.z); p[3] = (short)f2bf(f0.w);
        p[4] = (short)f2bf(f1.x); p[5] = (short)f2bf(f1.y);
        p[6] = (short)f2bf(f1.z); p[7] = (short)f2bf(f1.w);
        *(bf16x8*)(featb + (size_t)i * 8) = p;
    }
}

// --- K2: vertex normals via corner-list walk; float4 out ---
__global__ void k_vnorm(const float4* __restrict__ fnbuf4,
                        const int* __restrict__ head_f, const int* __restrict__ next_f,
                        float4* __restrict__ nrm4) {
    int v = blockIdx.x * 256 + threadIdx.x;
    if (v >= N_V) return;
    float nx = 0.f, ny = 0.f, nz = 0.f;
    int c = head_f[v];
    while (c >= 0) {
        float4 fn = fnbuf4[(unsigned)c / 3u];
        nx += fn.x; ny += fn.y; nz += fn.z;
        c = next_f[c];
    }
    float inv = 1.f / (sqrtf(nx * nx + ny * ny + nz * nz) + 1e-8f);
    float4 o;
    o.x = nx * inv; o.y = ny * inv; o.z = nz * inv; o.w = 0.f;
    nrm4[v] = o;
}

// --- K3: per-edge MLP. PUSH_DONE=0: classic (atomicExch + split-w pack).
//     PUSH_DONE=1: atomic-free; writes only nd.y = src | w15<<17 (w>0 => bf16 sign=0).
template<int PUSH_DONE>
__global__ void k_edge_t(const float* __restrict__ vtx, const int* __restrict__ edges,
                         const float4* __restrict__ nrm4,
                         const float* __restrict__ W1, const float* __restrict__ b1,
                         const float* __restrict__ W2, const float* __restrict__ b2,
                         int* __restrict__ head_e, uint2* __restrict__ enode) {
    __shared__ float sW1[96], sb1[32], sW2[192], sb2[6];
    int t = threadIdx.x;
    if (t < 96)  sW1[t] = W1[t];
    if (t < 32)  sb1[t] = b1[t];
    if (t < 192) sW2[t] = W2[t];
    if (t < 6)   sb2[t] = b2[t];
    __syncthreads();
    int e = blockIdx.x * blockDim.x + t;
    if (e >= N_E) return;
    int s = edges[e], d = edges[N_E + e];
    int old = 0;
    if (!PUSH_DONE) old = atomicExch(&head_e[d], e);   // issue early; hides under MLP
    float4 nv = nrm4[s];
    float dx = vtx[3 * d] - vtx[3 * s];
    float dy = vtx[3 * d + 1] - vtx[3 * s + 1];
    float dz = vtx[3 * d + 2] - vtx[3 * s + 2];
    float nx = nv.x, ny = nv.y, nz = nv.z;
    float dp = dx * nx + dy * ny + dz * nz;
    float tx = dx - dp * nx, ty = dy - dp * ny, tz = dz - dp * nz;
    float th0 = sb2[0], th1 = sb2[1], th2 = sb2[2], th3 = sb2[3], th4 = sb2[4], th5 = sb2[5];
    #pragma unroll
    for (int j = 0; j < 32; j++) {
        float h = tx * sW1[j] + ty * sW1[32 + j] + tz * sW1[64 + j] + sb1[j];
        h = fmaxf(h, 0.f);
        const float* w2r = &sW2[j * 6];
        th0 += h * w2r[0]; th1 += h * w2r[1]; th2 += h * w2r[2];
        th3 += h * w2r[3]; th4 += h * w2r[4]; th5 += h * w2r[5];
    }
    float ux = th0 * tx + th1 * ty + th2 * tz;
    float uy = th1 * tx + th3 * ty + th4 * tz;
    float uz = th2 * tx + th4 * ty + th5 * tz;
    float q = ux * ux + uy * uy + uz * uz;
    float w = expf(-q);
    unsigned int w16 = f2bf(w);
    if (!PUSH_DONE) {
        uint2 nd;
        nd.x = (unsigned int)(old + 1) | ((w16 & 0xFFFu) << 20);
        nd.y = (unsigned int)s | ((w16 >> 12) << 17);
        enode[e] = nd;
    } else {
        ((unsigned int*)enode)[2 * (size_t)e + 1] = (unsigned int)s | (w16 << 17);
    }
}

// --- K4: FUSED aggregate + GEMM + bias + stats partials. Proven shape: 512 thr,
// 128 rows, 16-lane groups x 4 chains, 8 floats/lane. STYLE: 0=split-w fp32 gather,
// 1=hi15-w fp32 gather, 2=hi15-w bf16 gather (halved bytes).
template<int STYLE>
__global__ __launch_bounds__(512) void k_fused_t(const float* __restrict__ feat,
                                                 const unsigned short* __restrict__ featb,
                                                 const int* __restrict__ head_e,
                                                 const uint2* __restrict__ enode,
                                                 const unsigned short* __restrict__ Wb,
                                                 const float* __restrict__ blin,
                                                 float* __restrict__ out,
                                                 float* __restrict__ partials) {
    __shared__ __align__(16) unsigned short At[128 * 136];
    __shared__ float gs[128];
    int t = threadIdx.x;
    int g = t >> 4;
    int gl = t & 15;
    int vb = blockIdx.x * 128 + g * 4;

    float4 a0l = {0,0,0,0}, a0h = {0,0,0,0};
    float4 a1l = {0,0,0,0}, a1h = {0,0,0,0};
    float4 a2l = {0,0,0,0}, a2h = {0,0,0,0};
    float4 a3l = {0,0,0,0}, a3h = {0,0,0,0};
    float d0 = 0.f, d1 = 0.f, d2 = 0.f, d3 = 0.f;
    int e0 = (vb + 0 < N_V) ? head_e[vb + 0] : -1;
    int e1 = (vb + 1 < N_V) ? head_e[vb + 1] : -1;
    int e2 = (vb + 2 < N_V) ? head_e[vb + 2] : -1;
    int e3 = (vb + 3 < N_V) ? head_e[vb + 3] : -1;

#define CHAIN_STEP(eV, aL, aH, dV)                                                   \
    if (eV >= 0) {                                                                   \
        uint2 nd = enode[eV];                                                        \
        unsigned int w16 = (STYLE == 0)                                              \
            ? ((nd.x >> 20) | (((nd.y >> 17) & 0xFu) << 12))                         \
            : (nd.y >> 17);                                                          \
        float w = __builtin_bit_cast(float, w16 << 16);                              \
        unsigned int src = nd.y & 0x1FFFFu;                                          \
        if (STYLE < 2) {                                                             \
            const float4* fp = (const float4*)(feat + (size_t)src * 128 + 8 * gl);   \
            float4 f0 = fp[0], f1 = fp[1];                                           \
            aL.x += w * f0.x; aL.y += w * f0.y; aL.z += w * f0.z; aL.w += w * f0.w;  \
            aH.x += w * f1.x; aH.y += w * f1.y; aH.z += w * f1.z; aH.w += w * f1.w;  \
        } else {                                                                     \
            bf16x8 v = *(const bf16x8*)(featb + (size_t)src * 128 + 8 * gl);         \
            aL.x += w * bf2f(v[0]); aL.y += w * bf2f(v[1]);                          \
            aL.z += w * bf2f(v[2]); aL.w += w * bf2f(v[3]);                          \
            aH.x += w * bf2f(v[4]); aH.y += w * bf2f(v[5]);                          \
            aH.z += w * bf2f(v[6]); aH.w += w * bf2f(v[7]);                          \
        }                                                                            \
        dV += w;                                                                     \
        eV = (int)(nd.x & 0xFFFFFu) - 1;                                             \
    }

    while ((e0 >= 0) || (e1 >= 0) || (e2 >= 0) || (e3 >= 0)) {
        CHAIN_STEP(e0, a0l, a0h, d0)
        CHAIN_STEP(e1, a1l, a1h, d1)
        CHAIN_STEP(e2, a2l, a2h, d2)
        CHAIN_STEP(e3, a3l, a3h, d3)
    }
#undef CHAIN_STEP

    #pragma unroll
    for (int j = 0; j < 4; j++) {
        float4 al = (j == 0) ? a0l : (j == 1) ? a1l : (j == 2) ? a2l : a3l;
        float4 ah = (j == 0) ? a0h : (j == 1) ? a1h : (j == 2) ? a2h : a3h;
        float dn = (j == 0) ? d0 : (j == 1) ? d1 : (j == 2) ? d2 : d3;
        float inv = 1.f / (dn + 1e-5f);
        ushort4 p0, p1;
        p0.x = f2bf(al.x * inv); p0.y = f2bf(al.y * inv);
        p0.z = f2bf(al.z * inv); p0.w = f2bf(al.w * inv);
        p1.x = f2bf(ah.x * inv); p1.y = f2bf(ah.y * inv);
        p1.z = f2bf(ah.z * inv); p1.w = f2bf(ah.w * inv);
        int row = g * 4 + j;
        *(ushort4*)(&At[row * 136 + 8 * gl]) = p0;
        *(ushort4*)(&At[row * 136 + 8 * gl + 4]) = p1;
        if (gl == 0) gs[row] = dn * inv;
    }
    __syncthreads();

    // Phase 2: MFMA. wave id = column tile ct; 8 row tiles of 16.
    int ct = t >> 6;
    int lane = t & 63;
    int m = lane & 15, quad = lane >> 4;
    bf16x8 bfr[4];
    #pragma unroll
    for (int kk = 0; kk < 4; kk++)
        bfr[kk] = *(const bf16x8*)(Wb + (((kk * 8 + ct) * 64 + lane) << 3));
    float bl = blin[ct * 16 + m];
    float ssr = 0.f, qqr = 0.f;
    #pragma unroll
    for (int tile = 0; tile < 8; tile++) {
        f32x4 acc = (f32x4){0.f, 0.f, 0.f, 0.f};
        #pragma unroll
        for (int kk = 0; kk < 4; kk++) {
            bf16x8 af = *(const bf16x8*)(&At[(tile * 16 + m) * 136 + kk * 32 + quad * 8]);
            acc = __builtin_amdgcn_mfma_f32_16x16x32_bf16(af, bfr[kk], acc, 0, 0, 0);
        }
        int r0 = blockIdx.x * 128 + tile * 16;
        #pragma unroll
        for (int reg = 0; reg < 4; reg++) {
            int r = r0 + quad * 4 + reg;
            float g2 = gs[tile * 16 + quad * 4 + reg];
            float val = acc[reg] + bl * g2;
            if (r < N_V) out[(size_t)r * 128 + ct * 16 + m] = val;   // nt-store hurt: reverted
            ssr += val; qqr += val * val;
        }
    }
    ssr += __shfl_xor(ssr, 16); qqr += __shfl_xor(qqr, 16);
    ssr += __shfl_xor(ssr, 32); qqr += __shfl_xor(qqr, 32);
    if (quad == 0) {
        partials[(size_t)blockIdx.x * 256 + ct * 16 + m] = ssr;
        partials[(size_t)blockIdx.x * 256 + 128 + ct * 16 + m] = qqr;
    }
}

// --- K5: parallel partials reduction: one wave per column ---
__global__ __launch_bounds__(64) void k_rstats(const float* __restrict__ partials,
                                               float* __restrict__ stats) {
    int c = blockIdx.x;
    int lane = threadIdx.x;
    float s = 0.f, q = 0.f;
    for (int b = lane; b < FUSED_BLOCKS; b += 64) {
        s += partials[(size_t)b * 256 + c];
        q += partials[(size_t)b * 256 + 128 + c];
    }
    #pragma unroll
    for (int off = 32; off; off >>= 1) {
        s += __shfl_down(s, off);
        q += __shfl_down(q, off);
    }
    if (lane == 0) {
        float mu = s * (1.f / N_V);
        float var = (q - s * mu) * (1.f / (N_V - 1));
        float sd = sqrtf(fmaxf(var, 0.f));
        stats[c] = mu;
        stats[128 + c] = 1.f / (sd + 1e-5f);
    }
}

// --- K6: normalize + ELU, in place, float4 ---
__global__ void k_finalize(float* __restrict__ out, const float* __restrict__ stats) {
    int i = blockIdx.x * blockDim.x + threadIdx.x;
    if (i >= N_V * 32) return;
    float4 v = ((float4*)out)[i];
    int c0 = (i * 4) & 127;
    float mu0 = stats[c0], mu1 = stats[c0 + 1], mu2 = stats[c0 + 2], mu3 = stats[c0 + 3];
    float is0 = stats[128 + c0], is1 = stats[128 + c0 + 1], is2 = stats[128 + c0 + 2], is3 = stats[128 + c0 + 3];
    v.x = (v.x - mu0) * is0; v.y = (v.y - mu1) * is1;
    v.z = (v.z - mu2) * is2; v.w = (v.w - mu3) * is3;
    v.x = v.x > 0.f ? v.x : expm1f(v.x);
    v.y = v.y > 0.f ? v.y : expm1f(v.y);
    v.z = v.z > 0.f ? v.z : expm1f(v.z);
    v.w = v.w > 0.f ? v.w : expm1f(v.w);
    ((float4*)out)[i] = v;
}

extern "C" void kernel_launch(void* const* d_in, const int* in_sizes, int n_in,
                              void* d_out, int out_size, void* d_ws, size_t ws_size,
                              hipStream_t stream) {
    const float* feat  = (const float*)d_in[0];
    const float* vtx   = (const float*)d_in[1];
    const int*   edges = (const int*)d_in[2];
    const int*   faces = (const int*)d_in[3];
    const float* W1   = (const float*)d_in[4];
    const float* b1   = (const float*)d_in[5];
    const float* W2   = (const float*)d_in[6];
    const float* b2   = (const float*)d_in[7];
    const float* Wlin = (const float*)d_in[8];
    const float* blin = (const float*)d_in[9];
    float* out = (float*)d_out;
    float* ws = (float*)d_ws;

    // Tier selection by actual workspace size (fixed: Wb ends at 3,208,192 floats —
    // round 9 overlapped featb with Wb's upper half -> absmax 7.7):
    //   tier1 layout (no aliased enode): 3,208,192 floats = 12.83 MB
    //   tier2 adds featb (12.8M bf16):   9,608,192 floats = 38.43 MB
    const size_t NEED1 = 3208192u * 4u;
    const size_t NEED2 = 9608192u * 4u;
    int tier = (ws_size >= NEED2) ? 2 : (ws_size >= NEED1) ? 1 : 0;

    if (tier == 0) {
        // ===== proven 263us path (round 3/8 layout, aliased enode) =====
        int*   head_e   = (int*)ws;                              // 100000
        int*   head_f   = (int*)(ws + 100000);                   // 100000
        float4* nrm4    = (float4*)(ws + 200000);                // 100000 float4
        float* partials = ws + 100000;                           // alias
        int*   next_f   = (int*)(ws + 600128);                   // 600000
        float4* fnbuf4  = (float4*)(ws + 1200128);               // 200000 float4
        uint2* enode    = (uint2*)(ws + 600128);                 // alias next_f+fnbuf4
        unsigned short* Wb = (unsigned short*)(ws + 2000128);
        float* stats    = ws;

        hipMemsetAsync(head_e, 0xFF, 200000 * sizeof(int), stream);
        k_fn<<<FACE_BLOCKS + PACK_BLOCKS, 256, 0, stream>>>(vtx, faces, Wlin, edges, feat,
                                                            fnbuf4, head_f, next_f, Wb,
                                                            head_e, enode, nullptr);
        k_vnorm<<<(N_V + 255) / 256, 256, 0, stream>>>(fnbuf4, head_f, next_f, nrm4);
        k_edge_t<0><<<EDGE_BLOCKS, 256, 0, stream>>>(vtx, edges, nrm4, W1, b1, W2, b2,
                                                     head_e, enode);
        k_fused_t<0><<<FUSED_BLOCKS, 512, 0, stream>>>(feat, nullptr, head_e, enode, Wb,
                                                       blin, out, partials);
        k_rstats<<<128, 64, 0, stream>>>(partials, stats);
        k_finalize<<<(N_V * 32 + 255) / 256, 256, 0, stream>>>(out, stats);
    } else {
        // ===== tier >=1: non-aliased enode; edge push merged into k_fn =====
        //   head_e [0..100000) ; head_f [100000..200000) ; nrm4 [200000..600000)
        //   next_f [600000..1200000) ; fnbuf4 [1200000..2000000)
        //   enode  [2000000..3200000) ; Wb [3200000..3208192)
        //   featb  [3208192..9608192)  (tier 2)
        //   partials aliases [100000..300192) after k_edge; stats aliases ws[0..256)
        int*   head_e   = (int*)ws;
        int*   head_f   = (int*)(ws + 100000);
        float4* nrm4    = (float4*)(ws + 200000);
        float* partials = ws + 100000;
        int*   next_f   = (int*)(ws + 600000);
        float4* fnbuf4  = (float4*)(ws + 1200000);
        uint2* enode    = (uint2*)(ws + 2000000);
        unsigned short* Wb = (unsigned short*)(ws + 3200000);
        unsigned short* featb = (unsigned short*)(ws + 3208192);
        float* stats    = ws;

        hipMemsetAsync(head_e, 0xFF, 200000 * sizeof(int), stream);
        int fn_grid = FACE_BLOCKS + PACK_BLOCKS + EDGE_BLOCKS + (tier == 2 ? CONV_BLOCKS : 0);
        k_fn<<<fn_grid, 256, 0, stream>>>(vtx, faces, Wlin, edges, feat,
                                          fnbuf4, head_f, next_f, Wb,
                                          head_e, enode, featb);
        k_vnorm<<<(N_V + 255) / 256, 256, 0, stream>>>(fnbuf4, head_f, next_f, nrm4);
        k_edge_t<1><<<EDGE_BLOCKS, 256, 0, stream>>>(vtx, edges, nrm4, W1, b1, W2, b2,
                                                     head_e, enode);
        if (tier == 2)
            k_fused_t<2><<<FUSED_BLOCKS, 512, 0, stream>>>(feat, featb, head_e, enode, Wb,
                                                           blin, out, partials);
        else
            k_fused_t<1><<<FUSED_BLOCKS, 512, 0, stream>>>(feat, nullptr, head_e, enode, Wb,
                                                           blin, out, partials);
        k_rstats<<<128, 64, 0, stream>>>(partials, stats);
        k_finalize<<<(N_V * 32 + 255) / 256, 256, 0, stream>>>(out, stats);
    }
}

// Round 11
// 252.966 us; speedup vs baseline: 4.2609x; 1.0419x over previous
//
#include <hip/hip_runtime.h>
#include <hip/hip_bf16.h>
#include <math.h>

#define N_V 100000
#define N_E 600000
#define N_F 200000
// CIN = COUT = 128, H = 32

typedef __attribute__((ext_vector_type(8))) short bf16x8;
typedef __attribute__((ext_vector_type(4))) float f32x4;

#define FUSED_BLOCKS 782                    // ceil(100000/128); 128 rows per block
#define FACE_BLOCKS 782                     // ceil(200000/256)
#define EDGE_BLOCKS 2344                    // ceil(600000/256)
#define PACK_BLOCKS 64
#define CONV_BLOCKS 6250                    // 100000*128 bf16 conversions / (256*8)

__device__ __forceinline__ unsigned short f2bf(float f) {
    unsigned int u = __builtin_bit_cast(unsigned int, f);
    u += 0x7fffu + ((u >> 16) & 1u);   // round-to-nearest-even
    return (unsigned short)(u >> 16);
}
__device__ __forceinline__ float bf2f(short s) {
    return __builtin_bit_cast(float, ((unsigned int)(unsigned short)s) << 16);
}

// --- K1: faces (normals + corner list push) + Wlin pack (+ tier2: feat->bf16 conv).
// Edge-push measured IN k_fn: 1.2M atomics serialize at ~19G/s => 62us (round 10).
// Edge-push belongs in k_edge where MLP compute hides it (round 3 proof).
__global__ void k_fn(const float* __restrict__ vtx, const int* __restrict__ faces,
                     const float* __restrict__ Wlin, const float* __restrict__ feat,
                     float4* __restrict__ fnbuf4,
                     int* __restrict__ head_f, int* __restrict__ next_f,
                     unsigned short* __restrict__ Wb,
                     unsigned short* __restrict__ featb) {
    int b = blockIdx.x;
    int t = threadIdx.x;
    if (b < FACE_BLOCKS) {
        int f = b * 256 + t;
        if (f >= N_F) return;
        int i0 = faces[f], i1 = faces[N_F + f], i2 = faces[2 * N_F + f];
        #pragma unroll
        for (int j = 0; j < 3; j++) {
            int v = (j == 0) ? i0 : (j == 1 ? i1 : i2);
            int c = 3 * f + j;
            int old = atomicExch(&head_f[v], c);
            next_f[c] = old;
        }
        float ax = vtx[3 * i0], ay = vtx[3 * i0 + 1], az = vtx[3 * i0 + 2];
        float bx = vtx[3 * i1] - ax, by = vtx[3 * i1 + 1] - ay, bz = vtx[3 * i1 + 2] - az;
        float cx = vtx[3 * i2] - ax, cy = vtx[3 * i2 + 1] - ay, cz = vtx[3 * i2 + 2] - az;
        float4 fn;
        fn.x = by * cz - bz * cy;
        fn.y = bz * cx - bx * cz;
        fn.z = bx * cy - by * cx;
        fn.w = 0.f;
        fnbuf4[f] = fn;
    } else if (b < FACE_BLOCKS + PACK_BLOCKS) {
        // pack Wlin (fp32 [128,128]) into bf16 MFMA B-fragment order
        int i = (b - FACE_BLOCKS) * 256 + t;   // 0..16383
        int j = i & 7;
        int lane = (i >> 3) & 63;
        int ct = (i >> 9) & 7;
        int kk = i >> 12;
        int k = kk * 32 + (lane >> 4) * 8 + j;
        int n = ct * 16 + (lane & 15);
        Wb[i] = f2bf(Wlin[k * 128 + n]);
    } else {
        // tier 2: feat fp32 -> bf16 row-major copy (streamed, 8 elems/thread)
        int i = (b - FACE_BLOCKS - PACK_BLOCKS) * 256 + t;
        const float4* fp = (const float4*)(feat + (size_t)i * 8);
        float4 f0 = fp[0], f1 = fp[1];
        bf16x8 p;
        p[0] = (short)f2bf(f0.x); p[1] = (short)f2bf(f0.y);
        p[2] = (short)f2bf(f0.z); p[3] = (short)f2bf(f0.w);
        p[4] = (short)f2bf(f1.x); p[5] = (short)f2bf(f1.y);
        p[6] = (short)f2bf(f1.z); p[7] = (short)f2bf(f1.w);
        *(bf16x8*)(featb + (size_t)i * 8) = p;
    }
}

// --- K2: vertex normals via corner-list walk; float4 out ---
__global__ void k_vnorm(const float4* __restrict__ fnbuf4,
                        const int* __restrict__ head_f, const int* __restrict__ next_f,
                        float4* __restrict__ nrm4) {
    int v = blockIdx.x * 256 + threadIdx.x;
    if (v >= N_V) return;
    float nx = 0.f, ny = 0.f, nz = 0.f;
    int c = head_f[v];
    while (c >= 0) {
        float4 fn = fnbuf4[(unsigned)c / 3u];
        nx += fn.x; ny += fn.y; nz += fn.z;
        c = next_f[c];
    }
    float inv = 1.f / (sqrtf(nx * nx + ny * ny + nz * nz) + 1e-8f);
    float4 o;
    o.x = nx * inv; o.y = ny * inv; o.z = nz * inv; o.w = 0.f;
    nrm4[v] = o;
}

// --- K3: per-edge MLP + atomicExch list push (issued early; latency hides under MLP).
//     MODE 0: split-w pack (w lo12 in nd.x, hi4 in nd.y) — proven tier-0 format.
//     MODE 1: w15 pack (nd.y = src | w16<<17; bf16 sign bit 0 for w>0 => lossless).
template<int MODE>
__global__ void k_edge_t(const float* __restrict__ vtx, const int* __restrict__ edges,
                         const float4* __restrict__ nrm4,
                         const float* __restrict__ W1, const float* __restrict__ b1,
                         const float* __restrict__ W2, const float* __restrict__ b2,
                         int* __restrict__ head_e, uint2* __restrict__ enode) {
    __shared__ float sW1[96], sb1[32], sW2[192], sb2[6];
    int t = threadIdx.x;
    if (t < 96)  sW1[t] = W1[t];
    if (t < 32)  sb1[t] = b1[t];
    if (t < 192) sW2[t] = W2[t];
    if (t < 6)   sb2[t] = b2[t];
    __syncthreads();
    int e = blockIdx.x * blockDim.x + t;
    if (e >= N_E) return;
    int s = edges[e], d = edges[N_E + e];
    int old = atomicExch(&head_e[d], e);      // issue early; hides under MLP
    float4 nv = nrm4[s];
    float dx = vtx[3 * d] - vtx[3 * s];
    float dy = vtx[3 * d + 1] - vtx[3 * s + 1];
    float dz = vtx[3 * d + 2] - vtx[3 * s + 2];
    float nx = nv.x, ny = nv.y, nz = nv.z;
    float dp = dx * nx + dy * ny + dz * nz;
    float tx = dx - dp * nx, ty = dy - dp * ny, tz = dz - dp * nz;
    float th0 = sb2[0], th1 = sb2[1], th2 = sb2[2], th3 = sb2[3], th4 = sb2[4], th5 = sb2[5];
    #pragma unroll
    for (int j = 0; j < 32; j++) {
        float h = tx * sW1[j] + ty * sW1[32 + j] + tz * sW1[64 + j] + sb1[j];
        h = fmaxf(h, 0.f);
        const float* w2r = &sW2[j * 6];
        th0 += h * w2r[0]; th1 += h * w2r[1]; th2 += h * w2r[2];
        th3 += h * w2r[3]; th4 += h * w2r[4]; th5 += h * w2r[5];
    }
    float ux = th0 * tx + th1 * ty + th2 * tz;
    float uy = th1 * tx + th3 * ty + th4 * tz;
    float uz = th2 * tx + th4 * ty + th5 * tz;
    float q = ux * ux + uy * uy + uz * uz;
    float w = expf(-q);
    unsigned int w16 = f2bf(w);
    uint2 nd;
    if (MODE == 0) {
        nd.x = (unsigned int)(old + 1) | ((w16 & 0xFFFu) << 20);
        nd.y = (unsigned int)s | ((w16 >> 12) << 17);
    } else {
        nd.x = (unsigned int)(old + 1);
        nd.y = (unsigned int)s | (w16 << 17);   // top bit of w16 (sign=0) drops
    }
    enode[e] = nd;
}

// --- K4: FUSED aggregate + GEMM + bias + stats partials. Proven shape: 512 thr,
// 128 rows, 16-lane groups x 4 chains, 8 elems/lane. STYLE: 0=split-w fp32 gather,
// 2=w15 bf16 gather (halved bytes; featb ~L2-resident).
template<int STYLE>
__global__ __launch_bounds__(512) void k_fused_t(const float* __restrict__ feat,
                                                 const unsigned short* __restrict__ featb,
                                                 const int* __restrict__ head_e,
                                                 const uint2* __restrict__ enode,
                                                 const unsigned short* __restrict__ Wb,
                                                 const float* __restrict__ blin,
                                                 float* __restrict__ out,
                                                 float* __restrict__ partials) {
    __shared__ __align__(16) unsigned short At[128 * 136];
    __shared__ float gs[128];
    int t = threadIdx.x;
    int g = t >> 4;
    int gl = t & 15;
    int vb = blockIdx.x * 128 + g * 4;

    float4 a0l = {0,0,0,0}, a0h = {0,0,0,0};
    float4 a1l = {0,0,0,0}, a1h = {0,0,0,0};
    float4 a2l = {0,0,0,0}, a2h = {0,0,0,0};
    float4 a3l = {0,0,0,0}, a3h = {0,0,0,0};
    float d0 = 0.f, d1 = 0.f, d2 = 0.f, d3 = 0.f;
    int e0 = (vb + 0 < N_V) ? head_e[vb + 0] : -1;
    int e1 = (vb + 1 < N_V) ? head_e[vb + 1] : -1;
    int e2 = (vb + 2 < N_V) ? head_e[vb + 2] : -1;
    int e3 = (vb + 3 < N_V) ? head_e[vb + 3] : -1;

#define CHAIN_STEP(eV, aL, aH, dV)                                                   \
    if (eV >= 0) {                                                                   \
        uint2 nd = enode[eV];                                                        \
        unsigned int w16 = (STYLE == 0)                                              \
            ? ((nd.x >> 20) | (((nd.y >> 17) & 0xFu) << 12))                         \
            : (nd.y >> 17);                                                          \
        float w = __builtin_bit_cast(float, w16 << 16);                              \
        unsigned int src = nd.y & 0x1FFFFu;                                          \
        if (STYLE < 2) {                                                             \
            const float4* fp = (const float4*)(feat + (size_t)src * 128 + 8 * gl);   \
            float4 f0 = fp[0], f1 = fp[1];                                           \
            aL.x += w * f0.x; aL.y += w * f0.y; aL.z += w * f0.z; aL.w += w * f0.w;  \
            aH.x += w * f1.x; aH.y += w * f1.y; aH.z += w * f1.z; aH.w += w * f1.w;  \
        } else {                                                                     \
            bf16x8 v = *(const bf16x8*)(featb + (size_t)src * 128 + 8 * gl);         \
            aL.x += w * bf2f(v[0]); aL.y += w * bf2f(v[1]);                          \
            aL.z += w * bf2f(v[2]); aL.w += w * bf2f(v[3]);                          \
            aH.x += w * bf2f(v[4]); aH.y += w * bf2f(v[5]);                          \
            aH.z += w * bf2f(v[6]); aH.w += w * bf2f(v[7]);                          \
        }                                                                            \
        dV += w;                                                                     \
        eV = (int)(nd.x & 0xFFFFFu) - 1;                                             \
    }

    while ((e0 >= 0) || (e1 >= 0) || (e2 >= 0) || (e3 >= 0)) {
        CHAIN_STEP(e0, a0l, a0h, d0)
        CHAIN_STEP(e1, a1l, a1h, d1)
        CHAIN_STEP(e2, a2l, a2h, d2)
        CHAIN_STEP(e3, a3l, a3h, d3)
    }
#undef CHAIN_STEP

    #pragma unroll
    for (int j = 0; j < 4; j++) {
        float4 al = (j == 0) ? a0l : (j == 1) ? a1l : (j == 2) ? a2l : a3l;
        float4 ah = (j == 0) ? a0h : (j == 1) ? a1h : (j == 2) ? a2h : a3h;
        float dn = (j == 0) ? d0 : (j == 1) ? d1 : (j == 2) ? d2 : d3;
        float inv = 1.f / (dn + 1e-5f);
        ushort4 p0, p1;
        p0.x = f2bf(al.x * inv); p0.y = f2bf(al.y * inv);
        p0.z = f2bf(al.z * inv); p0.w = f2bf(al.w * inv);
        p1.x = f2bf(ah.x * inv); p1.y = f2bf(ah.y * inv);
        p1.z = f2bf(ah.z * inv); p1.w = f2bf(ah.w * inv);
        int row = g * 4 + j;
        *(ushort4*)(&At[row * 136 + 8 * gl]) = p0;
        *(ushort4*)(&At[row * 136 + 8 * gl + 4]) = p1;
        if (gl == 0) gs[row] = dn * inv;
    }
    __syncthreads();

    // Phase 2: MFMA. wave id = column tile ct; 8 row tiles of 16.
    int ct = t >> 6;
    int lane = t & 63;
    int m = lane & 15, quad = lane >> 4;
    bf16x8 bfr[4];
    #pragma unroll
    for (int kk = 0; kk < 4; kk++)
        bfr[kk] = *(const bf16x8*)(Wb + (((kk * 8 + ct) * 64 + lane) << 3));
    float bl = blin[ct * 16 + m];
    float ssr = 0.f, qqr = 0.f;
    #pragma unroll
    for (int tile = 0; tile < 8; tile++) {
        f32x4 acc = (f32x4){0.f, 0.f, 0.f, 0.f};
        #pragma unroll
        for (int kk = 0; kk < 4; kk++) {
            bf16x8 af = *(const bf16x8*)(&At[(tile * 16 + m) * 136 + kk * 32 + quad * 8]);
            acc = __builtin_amdgcn_mfma_f32_16x16x32_bf16(af, bfr[kk], acc, 0, 0, 0);
        }
        int r0 = blockIdx.x * 128 + tile * 16;
        #pragma unroll
        for (int reg = 0; reg < 4; reg++) {
            int r = r0 + quad * 4 + reg;
            float g2 = gs[tile * 16 + quad * 4 + reg];
            float val = acc[reg] + bl * g2;
            if (r < N_V) out[(size_t)r * 128 + ct * 16 + m] = val;
            ssr += val; qqr += val * val;
        }
    }
    ssr += __shfl_xor(ssr, 16); qqr += __shfl_xor(qqr, 16);
    ssr += __shfl_xor(ssr, 32); qqr += __shfl_xor(qqr, 32);
    if (quad == 0) {
        partials[(size_t)blockIdx.x * 256 + ct * 16 + m] = ssr;
        partials[(size_t)blockIdx.x * 256 + 128 + ct * 16 + m] = qqr;
    }
}

// --- K5: parallel partials reduction: one wave per column ---
__global__ __launch_bounds__(64) void k_rstats(const float* __restrict__ partials,
                                               float* __restrict__ stats) {
    int c = blockIdx.x;
    int lane = threadIdx.x;
    float s = 0.f, q = 0.f;
    for (int b = lane; b < FUSED_BLOCKS; b += 64) {
        s += partials[(size_t)b * 256 + c];
        q += partials[(size_t)b * 256 + 128 + c];
    }
    #pragma unroll
    for (int off = 32; off; off >>= 1) {
        s += __shfl_down(s, off);
        q += __shfl_down(q, off);
    }
    if (lane == 0) {
        float mu = s * (1.f / N_V);
        float var = (q - s * mu) * (1.f / (N_V - 1));
        float sd = sqrtf(fmaxf(var, 0.f));
        stats[c] = mu;
        stats[128 + c] = 1.f / (sd + 1e-5f);
    }
}

// --- K6: normalize + ELU, in place, float4 ---
__global__ void k_finalize(float* __restrict__ out, const float* __restrict__ stats) {
    int i = blockIdx.x * blockDim.x + threadIdx.x;
    if (i >= N_V * 32) return;
    float4 v = ((float4*)out)[i];
    int c0 = (i * 4) & 127;
    float mu0 = stats[c0], mu1 = stats[c0 + 1], mu2 = stats[c0 + 2], mu3 = stats[c0 + 3];
    float is0 = stats[128 + c0], is1 = stats[128 + c0 + 1], is2 = stats[128 + c0 + 2], is3 = stats[128 + c0 + 3];
    v.x = (v.x - mu0) * is0; v.y = (v.y - mu1) * is1;
    v.z = (v.z - mu2) * is2; v.w = (v.w - mu3) * is3;
    v.x = v.x > 0.f ? v.x : expm1f(v.x);
    v.y = v.y > 0.f ? v.y : expm1f(v.y);
    v.z = v.z > 0.f ? v.z : expm1f(v.z);
    v.w = v.w > 0.f ? v.w : expm1f(v.w);
    ((float4*)out)[i] = v;
}

extern "C" void kernel_launch(void* const* d_in, const int* in_sizes, int n_in,
                              void* d_out, int out_size, void* d_ws, size_t ws_size,
                              hipStream_t stream) {
    const float* feat  = (const float*)d_in[0];
    const float* vtx   = (const float*)d_in[1];
    const int*   edges = (const int*)d_in[2];
    const int*   faces = (const int*)d_in[3];
    const float* W1   = (const float*)d_in[4];
    const float* b1   = (const float*)d_in[5];
    const float* W2   = (const float*)d_in[6];
    const float* b2   = (const float*)d_in[7];
    const float* Wlin = (const float*)d_in[8];
    const float* blin = (const float*)d_in[9];
    float* out = (float*)d_out;
    float* ws = (float*)d_ws;

    // Shared aliased layout (round-3 proven):
    //   head_e [0,100000) ; head_f [100000,200000) ; nrm4 [200000,600000)
    //   partials alias [100000,300192) after k_edge
    //   next_f [600128,1200128) ; fnbuf4 [1200128,2000128)
    //   enode alias [600128,1800128) after k_vnorm
    //   Wb [2000128,2008320) ; featb [2008320,8408320) (tier 2 only)
    int*   head_e   = (int*)ws;
    int*   head_f   = (int*)(ws + 100000);
    float4* nrm4    = (float4*)(ws + 200000);
    float* partials = ws + 100000;
    int*   next_f   = (int*)(ws + 600128);
    float4* fnbuf4  = (float4*)(ws + 1200128);
    uint2* enode    = (uint2*)(ws + 600128);
    unsigned short* Wb = (unsigned short*)(ws + 2000128);
    unsigned short* featb = (unsigned short*)(ws + 2008320);
    float* stats    = ws;

    // tier 2 needs featb: 8,408,320 floats = 33.63 MB (ws proven >= 38.4 MB in r9)
    const size_t NEED2 = 8408320u * 4u;
    int tier2 = (ws_size >= NEED2) ? 1 : 0;

    hipMemsetAsync(head_e, 0xFF, 200000 * sizeof(int), stream);   // head_e + head_f

    int fn_grid = FACE_BLOCKS + PACK_BLOCKS + (tier2 ? CONV_BLOCKS : 0);
    k_fn<<<fn_grid, 256, 0, stream>>>(vtx, faces, Wlin, feat, fnbuf4,
                                      head_f, next_f, Wb, tier2 ? featb : nullptr);
    k_vnorm<<<(N_V + 255) / 256, 256, 0, stream>>>(fnbuf4, head_f, next_f, nrm4);
    if (tier2) {
        k_edge_t<1><<<EDGE_BLOCKS, 256, 0, stream>>>(vtx, edges, nrm4, W1, b1, W2, b2,
                                                     head_e, enode);
        k_fused_t<2><<<FUSED_BLOCKS, 512, 0, stream>>>(feat, featb, head_e, enode, Wb,
                                                       blin, out, partials);
    } else {
        k_edge_t<0><<<EDGE_BLOCKS, 256, 0, stream>>>(vtx, edges, nrm4, W1, b1, W2, b2,
                                                     head_e, enode);
        k_fused_t<0><<<FUSED_BLOCKS, 512, 0, stream>>>(feat, nullptr, head_e, enode, Wb,
                                                       blin, out, partials);
    }
    k_rstats<<<128, 64, 0, stream>>>(partials, stats);
    k_finalize<<<(N_V * 32 + 255) / 256, 256, 0, stream>>>(out, stats);
}